// Round 10
// baseline (249.037 us; speedup 1.0000x reference)
//
#include <hip/hip_runtime.h>

#define NEG (-10000.0f)
#define START_TAG 62
#define STOP_TAG 63
#define SLEN 512
#define BATCH 512
#define NTAG 64

__device__ __forceinline__ float readlane_f(float v, int lane) {
    return __uint_as_float(__builtin_amdgcn_readlane(__float_as_uint(v), lane));
}

// shfl_xor within 32-lane halves via ds_swizzle immediate (bitmode):
// src_lane = ((i & 0x1F) | 0) ^ XMASK  -- per 32-half, XMASK < 32.
template <int XMASK>
__device__ __forceinline__ float swz_xor(float v) {
    return __uint_as_float(__builtin_amdgcn_ds_swizzle(
        __float_as_uint(v), (XMASK << 10) | 0x1F));
}

// quad_perm DPP broadcast (xor within 4 lanes), pure VALU.
template <int CTRL>
__device__ __forceinline__ float dpp_qp(float v) {
    return __uint_as_float(__builtin_amdgcn_mov_dpp(
        __float_as_uint(v), CTRL, 0xF, 0xF, true));
}
#define QP_X1 0xB1 // [1,0,3,2]  xor 1
#define QP_X2 0x4E // [2,3,0,1]  xor 2
#define QP_X3 0x1B // [3,2,1,0]  xor 3

// One wave per batch; lane j = tag j.
//
// Round-14: broadcast scoreboard (cyc/step): readlane-adjacent 872,
// readlane-dist8 757, LDS+manual-sched 660-710, LDS compiler-sched 590 (R3,
// best). All roundtrip q through a shared structure. New structure: XOR
// decomposition of the matvec -- with i = j^m,
//   acc_j = sum_m shfl_xor(q, m) * ex[m],   ex[m] = E[j^m][j] per lane,
// m = mh ^ ml: ml in {0..3} via quad_perm DPP (VALU), mh via 14 ds_swizzle
// (xor<=28, per-32-half) + 1 ds_bpermute (the 32-crossing). No ds_write ->
// ds_read turnaround, no bulk lgkmcnt drain; output stays in lane j.
//
// Exp-space recursion (verified rounds 7-13):
//   q'_j  = acc_j * exp(f_j) * rinv,  rinv = 2^-k exact from prior acc[lane0]
//   logz  = log(sum_j q_j e^tstop_j) + C0 + ktot*ln2
__global__ __launch_bounds__(64) __attribute__((amdgpu_waves_per_eu(1, 1)))
void crf_fwd(const float* __restrict__ feats,
             const int* __restrict__ tags,
             const float* __restrict__ mask,
             const float* __restrict__ trans,
             float* __restrict__ diff /* [BATCH] */) {
    const int b = blockIdx.x;
    const int j = threadIdx.x; // tag lane 0..63

    __shared__ float smask[SLEN]; // wave-uniform mask column

    // ---- ex[m] = exp(trans[j^m][j]) : xor-indexed E column, 64 VGPRs ----
    float ex[NTAG];
    float colsum = 0.0f;
#pragma unroll
    for (int m = 0; m < NTAG; ++m) {
        ex[m] = __expf(trans[((j ^ m) << 6) + j]); // exp(NEG) -> 0, desired
        colsum += ex[m];
    }
    const float tstop = trans[STOP_TAG * NTAG + j];

    // ---- mask column preload (regs reused by epilogue 2) ----
    float mreg[8];
#pragma unroll
    for (int k = 0; k < 8; ++k) mreg[k] = mask[(64 * k + j) * BATCH + b];
#pragma unroll
    for (int k = 0; k < 8; ++k) smask[64 * k + j] = mreg[k];

    // ---- step 0 (exact analytic; trans[START,:]==NEG) ----
    float f_s0 = feats[(size_t)b * NTAG + j]; // feats[0][b][j]
    float m0 = readlane_f(mreg[0], 0);
    float alpha0 = (m0 > 0.0f) ? (NEG + log1pf(colsum) + f_s0)
                               : ((j == START_TAG) ? 0.0f : NEG);
    const float C0 = readlane_f(alpha0, START_TAG);
    float q = __expf(alpha0 - C0); // cold: exp(NEG)->0 except START lane = 1

    if (j == 0) smask[0] = 0.0f; // s=0 loop iteration is a masked no-op
    __syncthreads(); // single wave: cheap; orders smask init before loop reads

    const int a32 = ((j ^ 32) << 2); // bpermute byte address for the 32-swap

    // ---- feats ring prefetch depth 4 (only vmcnt loads in the loop) ----
    const float* fp = feats + (size_t)b * NTAG + j;
    float fr[4];
#pragma unroll
    for (int t = 0; t < 4; ++t) fr[t] = fp[(size_t)t * BATCH * NTAG];

    float rinv = 1.0f; // wave-uniform pending normalizer 2^-kcur
    int kcur = 0;      // exponent embedded in rinv
    int ktot = 0;      // sum of APPLIED exponents

    for (int blk = 0; blk < 128; ++blk) {
#pragma unroll
        for (int t = 0; t < 4; ++t) {
            const int s = blk * 4 + t;

            const float mk = smask[s]; // uniform ds_read_b32, off-chain

            // ---- off-chain: exp(f), prefetch, scale prep ----
            float ef = __expf(fr[t]); // operand loaded 4 steps ago
            int sp = s + 4;
            if (sp > SLEN - 1) sp = SLEN - 1; // tail garbage, never consumed
            fr[t] = fp[(size_t)sp * BATCH * NTAG];
            float efr = ef * rinv; // rinv known from last step

            // ---- XOR-decomposed broadcast matvec ----
            // half 2 source: q32_j = q_{j^32}
            float q32 = __uint_as_float(__builtin_amdgcn_ds_bpermute(
                a32, __float_as_uint(q)));

            float acc0, acc1, acc2, acc3, qc;
            // g=0 (mh=0): identity
            acc0 = q * ex[0];
            acc1 = dpp_qp<QP_X1>(q) * ex[1];
            acc2 = dpp_qp<QP_X2>(q) * ex[2];
            acc3 = dpp_qp<QP_X3>(q) * ex[3];
#define GRP(QSRC, BASE)                                          \
    acc0 = fmaf((QSRC), ex[(BASE) + 0], acc0);                   \
    acc1 = fmaf(dpp_qp<QP_X1>(QSRC), ex[(BASE) + 1], acc1);      \
    acc2 = fmaf(dpp_qp<QP_X2>(QSRC), ex[(BASE) + 2], acc2);      \
    acc3 = fmaf(dpp_qp<QP_X3>(QSRC), ex[(BASE) + 3], acc3);
            qc = swz_xor<4>(q);    GRP(qc, 4);
            qc = swz_xor<8>(q);    GRP(qc, 8);
            qc = swz_xor<12>(q);   GRP(qc, 12);
            qc = swz_xor<16>(q);   GRP(qc, 16);
            qc = swz_xor<20>(q);   GRP(qc, 20);
            qc = swz_xor<24>(q);   GRP(qc, 24);
            qc = swz_xor<28>(q);   GRP(qc, 28);
            GRP(q32, 32);
            qc = swz_xor<4>(q32);  GRP(qc, 36);
            qc = swz_xor<8>(q32);  GRP(qc, 40);
            qc = swz_xor<12>(q32); GRP(qc, 44);
            qc = swz_xor<16>(q32); GRP(qc, 48);
            qc = swz_xor<20>(q32); GRP(qc, 52);
            qc = swz_xor<24>(q32); GRP(qc, 56);
            qc = swz_xor<28>(q32); GRP(qc, 60);
#undef GRP
            float acc_s = (acc0 + acc1) + (acc2 + acc3);

            float qn = acc_s * efr;
            bool upd = (mk > 0.0f);
            q = upd ? qn : q; // masked step: q unchanged

            // ---- renormalizer bookkeeping (off the critical chain) ----
            ktot = upd ? (ktot + kcur) : ktot; // kcur was applied this step
            unsigned a0u = __builtin_amdgcn_readfirstlane(__float_as_uint(acc_s));
            int ke = (int)((a0u >> 23) & 0xffu) - 127; // floor exp of acc[0] (>0)
            ke = (ke < -60) ? -60 : ((ke > 60) ? 60 : ke); // runaway guard
            float rnew = __uint_as_float((unsigned)(127 - ke) << 23); // exact 2^-ke
            rinv = upd ? rnew : rinv;
            kcur = upd ? ke : kcur;
        }
    }

    // ---- epilogue 1: logz = log(sum_j q_j * exp(tstop_j)) + C0 + ktot*ln2 ----
    float et = __expf(tstop); // tstop[STOP]=NEG -> 0; q[STOP]=0 anyway
    float pe = q * et;
#pragma unroll
    for (int w = 32; w >= 1; w >>= 1) pe += __shfl_xor(pe, w, 64);
    float logz = __logf(pe) + C0 + (float)ktot * 0.6931471805599453f;

    // ---- epilogue 2: true-path score; lanes parallel over time steps ----
    float psc = 0.0f, pms = 0.0f;
#pragma unroll
    for (int k = 0; k < 8; ++k) {
        int s = j + 64 * k;
        int tg = tags[s * BATCH + b];
        float mkk = mreg[k]; // this lane's preloaded mask[s]
        int tprev = (s == 0) ? START_TAG : tags[(s - 1) * BATCH + b];
        float em = feats[((size_t)s * BATCH + b) * NTAG + tg];
        psc = fmaf(em + trans[tprev * NTAG + tg], mkk, psc);
        pms += mkk;
    }
#pragma unroll
    for (int w = 32; w >= 1; w >>= 1) {
        psc += __shfl_xor(psc, w, 64);
        pms += __shfl_xor(pms, w, 64);
    }

    if (j == 0) {
        int last_idx = (int)(pms + 0.5f) - 1;
        int ltag = tags[last_idx * BATCH + b];
        float score = psc + trans[ltag * NTAG + STOP_TAG];
        diff[b] = logz - score;
    }
}

__global__ __launch_bounds__(512) void crf_reduce(const float* __restrict__ diff,
                                                  float* __restrict__ out) {
    __shared__ float sdata[8];
    int t = threadIdx.x;
    float val = diff[t];
#pragma unroll
    for (int w = 32; w >= 1; w >>= 1)
        val += __shfl_xor(val, w, 64);
    if ((t & 63) == 0) sdata[t >> 6] = val;
    __syncthreads();
    if (t == 0) {
        float ssum = 0.0f;
        for (int i = 0; i < 8; ++i) ssum += sdata[i];
        out[0] = ssum * (1.0f / (float)BATCH);
    }
}

extern "C" void kernel_launch(void* const* d_in, const int* in_sizes, int n_in,
                              void* d_out, int out_size, void* d_ws, size_t ws_size,
                              hipStream_t stream) {
    const float* feats = (const float*)d_in[0];
    const int* tags = (const int*)d_in[1];
    const float* mask = (const float*)d_in[2];
    const float* trans = (const float*)d_in[3];
    float* out = (float*)d_out;
    float* diff = (float*)d_ws; // 512 floats

    crf_fwd<<<BATCH, 64, 0, stream>>>(feats, tags, mask, trans, diff);
    crf_reduce<<<1, 512, 0, stream>>>(diff, out);
}

// Round 12
// 235.466 us; speedup vs baseline: 1.0576x; 1.0576x over previous
//
#include <hip/hip_runtime.h>

#define NEG (-10000.0f)
#define START_TAG 62
#define STOP_TAG 63
#define SLEN 512
#define BATCH 512
#define NTAG 64

typedef float f32x4 __attribute__((ext_vector_type(4)));

__device__ __forceinline__ float readlane_f(float v, int lane) {
    return __uint_as_float(__builtin_amdgcn_readlane(__float_as_uint(v), lane));
}

// TWO waves per batch; lane j = tag j; wave h owns i-half [32h, 32h+32).
//
// Round-16: round-15's bench died at container level; audit found no hang
// (in-loop barrier is wave-uniform), no harmful race (qbuf written by both
// waves with bitwise-identical values -- IEEE add commutes; each wave reads
// only bytes it wrote itself, in-order DS), and no resource overrun (LDS
// ~3.8 KB, VGPR ~105 < 132). Session timing logs show infra flakiness
// (push_in_npz_s 5e-7 .. 1025 s). Resubmitting byte-identical device code.
//
// Design (round 15): five broadcast structures all lost to R3's 590 cyc/step;
// chain = LDS roundtrip + 64-FMA serial issue + ~120 cyc DS return. New axis:
// HALVE per-wave work. Wave h: partial_j = sum_{i in half h} q_i*E_ij =
// 32 FMA + 8 ds_read_b128 (one-step-ahead lookahead now fits the 132-VGPR
// cap). Halves combine via 1 ds_read_b32/lane (1 barrier/step, parity-dbuf).
//
// Exp-space recursion (verified rounds 7-14):
//   q'_j  = (p0_j + p1_j) * exp(f_j) * rinv,  rinv = 2^-k exact (lane0 exp)
//   logz  = log(sum_j q_j e^tstop_j) + C0 + ktot*ln2
__global__ __launch_bounds__(128) __attribute__((amdgpu_waves_per_eu(1, 1)))
void crf_fwd(const float* __restrict__ feats,
             const int* __restrict__ tags,
             const float* __restrict__ mask,
             const float* __restrict__ trans,
             float* __restrict__ diff /* [BATCH] */) {
    const int b = blockIdx.x;
    const int tid = threadIdx.x;
    const int h = tid >> 6;  // wave 0/1
    const int j = tid & 63;  // tag lane

    __shared__ float smask[SLEN + 1];            // +1: zero pad for mk pipeline
    __shared__ __align__(16) float qbuf[NTAG];   // current q (both waves write same)
    __shared__ float pbuf[2][2][NTAG];           // partial exchange, parity-dbuf
    __shared__ float csum2[2][NTAG];             // one-time colsum exchange

    // ---- E half-column in registers: e[ii] = exp(trans[32h+ii][j]) ----
    float e[32];
    float halfsum = 0.0f;
#pragma unroll
    for (int ii = 0; ii < 32; ++ii) {
        e[ii] = __expf(trans[(32 * h + ii) * NTAG + j]); // exp(NEG)->0, desired
        halfsum += e[ii];
    }
    csum2[h][j] = halfsum;
    const float tstop = trans[STOP_TAG * NTAG + j];

    // ---- mask column staging: wave h stages rows [256h, 256h+256) ----
#pragma unroll
    for (int k = 0; k < 4; ++k) {
        int row = 64 * (4 * h + k) + j;
        smask[row] = mask[row * BATCH + b];
    }
    if (tid == 0) { smask[SLEN] = 0.0f; }
    __syncthreads(); // csum2 + smask visible

    const float colsum = csum2[0][j] + csum2[1][j];

    // ---- step 0 (exact analytic; trans[START,:]==NEG) ----
    float f_s0 = feats[(size_t)b * NTAG + j]; // feats[0][b][j]
    float m0 = mask[b];                       // mask[0][b], one-time uniform load
    float alpha0 = (m0 > 0.0f) ? (NEG + log1pf(colsum) + f_s0)
                               : ((j == START_TAG) ? 0.0f : NEG);
    const float C0 = readlane_f(alpha0, START_TAG);
    float q = __expf(alpha0 - C0); // cold: exp(NEG)->0 except START lane = 1

    qbuf[j] = q; // both waves write identical values
    if (tid == 0) smask[0] = 0.0f; // s=0 loop iteration is a masked no-op
    __syncthreads();

    // ---- initial broadcast of own i-half: 8 x ds_read_b128 ----
    const f32x4* qv = (const f32x4*)&qbuf[32 * h];
    f32x4 Q[8];
#pragma unroll
    for (int c = 0; c < 8; ++c) Q[c] = qv[c];
    float mk = smask[0]; // == 0 (dummy step 0)

    // ---- feats ring prefetch depth 4 (only vmcnt loads in the loop) ----
    const float* fp = feats + (size_t)b * NTAG + j;
    float fr[4];
#pragma unroll
    for (int t = 0; t < 4; ++t) fr[t] = fp[(size_t)t * BATCH * NTAG];

    float rinv = 1.0f; // wave-uniform pending normalizer 2^-kcur
    int kcur = 0;      // exponent embedded in rinv
    int ktot = 0;      // sum of APPLIED exponents

    for (int blk = 0; blk < 128; ++blk) {
#pragma unroll
        for (int t = 0; t < 4; ++t) {
            const int s = blk * 4 + t;
            const int ph = s & 1;

            // ---- off-chain: exp(f), prefetch, scale prep ----
            float ef = __expf(fr[t]); // operand loaded 4 steps ago
            int sp = s + 4;
            if (sp > SLEN - 1) sp = SLEN - 1; // tail garbage, never consumed
            fr[t] = fp[(size_t)sp * BATCH * NTAG];
            float efr = ef * rinv; // rinv known from last step

            // ---- half-tree: 32 FMA over own i-half (Q preloaded last step) --
            float a0 = 0.0f, a1 = 0.0f, a2 = 0.0f, a3 = 0.0f;
#pragma unroll
            for (int c = 0; c < 8; ++c) {
                a0 = fmaf(Q[c].x, e[4 * c + 0], a0);
                a1 = fmaf(Q[c].y, e[4 * c + 1], a1);
                a2 = fmaf(Q[c].z, e[4 * c + 2], a2);
                a3 = fmaf(Q[c].w, e[4 * c + 3], a3);
            }
            float p = (a0 + a1) + (a2 + a3);

            // ---- cross-wave exchange: 1 write + barrier + 1 read ----
            pbuf[ph][h][j] = p;
            __syncthreads();
            float po = pbuf[ph][1 - h][j];
            float acc_s = p + po; // IEEE add commutes: identical in both waves

            float qn = acc_s * efr;
            bool upd = (mk > 0.0f);
            q = upd ? qn : q; // masked step: q unchanged

            // publish q' (both waves, identical values; in-wave order suffices)
            qbuf[j] = q;
            // issue next step's broadcast reads immediately (hide under tail)
#pragma unroll
            for (int c = 0; c < 8; ++c) Q[c] = qv[c];
            mk = smask[s + 1]; // s=511 -> zero pad slot

            // ---- renormalizer bookkeeping (off the critical chain) ----
            ktot = upd ? (ktot + kcur) : ktot; // kcur was applied this step
            unsigned a0u = __builtin_amdgcn_readfirstlane(__float_as_uint(acc_s));
            int ke = (int)((a0u >> 23) & 0xffu) - 127; // floor exp of acc[lane0]
            ke = (ke < -60) ? -60 : ((ke > 60) ? 60 : ke); // runaway guard
            float rnew = __uint_as_float((unsigned)(127 - ke) << 23); // exact 2^-ke
            rinv = upd ? rnew : rinv;
            kcur = upd ? ke : kcur;
        }
    }

    if (h != 0) return; // epilogues in wave 0 only (q/ktot identical in both)

    // ---- epilogue 1: logz = log(sum_j q_j * exp(tstop_j)) + C0 + ktot*ln2 ----
    float et = __expf(tstop); // tstop[STOP]=NEG -> 0; q[STOP]=0 anyway
    float pe = q * et;
#pragma unroll
    for (int w = 32; w >= 1; w >>= 1) pe += __shfl_xor(pe, w, 64);
    float logz = __logf(pe) + C0 + (float)ktot * 0.6931471805599453f;

    // ---- epilogue 2: true-path score; lanes parallel over time steps ----
    float psc = 0.0f, pms = 0.0f;
#pragma unroll
    for (int k = 0; k < 8; ++k) {
        int s = j + 64 * k;
        int tg = tags[s * BATCH + b];
        float mkk = mask[(64 * k + j) * BATCH + b]; // reload (off perf path)
        int tprev = (s == 0) ? START_TAG : tags[(s - 1) * BATCH + b];
        float em = feats[((size_t)s * BATCH + b) * NTAG + tg];
        psc = fmaf(em + trans[tprev * NTAG + tg], mkk, psc);
        pms += mkk;
    }
#pragma unroll
    for (int w = 32; w >= 1; w >>= 1) {
        psc += __shfl_xor(psc, w, 64);
        pms += __shfl_xor(pms, w, 64);
    }

    if (tid == 0) {
        int last_idx = (int)(pms + 0.5f) - 1;
        int ltag = tags[last_idx * BATCH + b];
        float score = psc + trans[ltag * NTAG + STOP_TAG];
        diff[b] = logz - score;
    }
}

__global__ __launch_bounds__(512) void crf_reduce(const float* __restrict__ diff,
                                                  float* __restrict__ out) {
    __shared__ float sdata[8];
    int t = threadIdx.x;
    float val = diff[t];
#pragma unroll
    for (int w = 32; w >= 1; w >>= 1)
        val += __shfl_xor(val, w, 64);
    if ((t & 63) == 0) sdata[t >> 6] = val;
    __syncthreads();
    if (t == 0) {
        float ssum = 0.0f;
        for (int i = 0; i < 8; ++i) ssum += sdata[i];
        out[0] = ssum * (1.0f / (float)BATCH);
    }
}

extern "C" void kernel_launch(void* const* d_in, const int* in_sizes, int n_in,
                              void* d_out, int out_size, void* d_ws, size_t ws_size,
                              hipStream_t stream) {
    const float* feats = (const float*)d_in[0];
    const int* tags = (const int*)d_in[1];
    const float* mask = (const float*)d_in[2];
    const float* trans = (const float*)d_in[3];
    float* out = (float*)d_out;
    float* diff = (float*)d_ws; // 512 floats

    crf_fwd<<<BATCH, 128, 0, stream>>>(feats, tags, mask, trans, diff);
    crf_reduce<<<1, 512, 0, stream>>>(diff, out);
}